// Round 12
// baseline (222.353 us; speedup 1.0000x reference)
//
#include <hip/hip_runtime.h>

typedef unsigned short u16;
typedef __bf16 bf16x8 __attribute__((ext_vector_type(8)));
typedef float f32x4 __attribute__((ext_vector_type(4)));
typedef unsigned short u16x4 __attribute__((ext_vector_type(4)));

#define LOG2E 1.44269504088896340736f
#define LDK 1040   // padded Kp row (u16): breaks 2KB channel aliasing
#define LDV 2080   // padded Vt row (u16): breaks 4KB channel aliasing
// mantissa-magic exp2->bf16: fmaf(s,128,12582912+16248) quantizes s*128+16248
// into the fp32 mantissa; low 16 bits are bf16 of ~2^s (Mineiro, bf16-direct).
#define EXPM16 12599160.0f

__device__ __forceinline__ u16 f2bf(float f) {
  unsigned u = __float_as_uint(f);
  u += 0x7FFFu + ((u >> 16) & 1u);
  return (u16)(u >> 16);
}

__device__ __forceinline__ void load_lds16(const void* g, void* l) {
  __builtin_amdgcn_global_load_lds(
      (__attribute__((address_space(1))) void*)g,
      (__attribute__((address_space(3))) void*)l, 16, 0, 0);
}

__device__ __forceinline__ f32x4 mfma16(bf16x8 a, bf16x8 b, f32x4 c) {
  return __builtin_amdgcn_mfma_f32_16x16x32_bf16(a, b, c, 0, 0, 0);
}

// ------- merged pre-pass: blocks [0,8192) cast q/kv -> bf16; [8192,12288) W^T ----
__global__ __launch_bounds__(256) void pre_kernel(
    const float* __restrict__ q, const float* __restrict__ kv,
    u16* __restrict__ Xq, u16* __restrict__ Xkv,
    const float* __restrict__ Wq, const float* __restrict__ Wk,
    const float* __restrict__ Wv, const float* __restrict__ Wo,
    u16* __restrict__ Wqt, u16* __restrict__ Wkt,
    u16* __restrict__ Wvt, u16* __restrict__ Wot) {
  __shared__ float tile[32][33];
  const int bid = blockIdx.x;
  if (bid < 8192) {
    const int n4each = 4096 * 256;
    int i = bid * 256 + threadIdx.x;
    const float* src; u16* dst; int j;
    if (i < n4each) { src = q; dst = Xq; j = i; }
    else            { src = kv; dst = Xkv; j = i - n4each; }
    const float4 v = ((const float4*)src)[j];
    u16x4 o;
    o.x = f2bf(v.x); o.y = f2bf(v.y); o.z = f2bf(v.z); o.w = f2bf(v.w);
    ((u16x4*)dst)[j] = o;
    return;
  }
  const int t = bid - 8192;
  const int z = t >> 10, rem = t & 1023;
  const float* W; u16* Wt;
  switch (z) {
    case 0: W = Wq; Wt = Wqt; break;
    case 1: W = Wk; Wt = Wkt; break;
    case 2: W = Wv; Wt = Wvt; break;
    default: W = Wo; Wt = Wot; break;
  }
  const int tx = threadIdx.x & 31, ty = threadIdx.x >> 5;  // 32x8
  const int n0 = (rem & 31) * 32, k0 = (rem >> 5) * 32;
#pragma unroll
  for (int i = 0; i < 4; i++)
    tile[ty + i * 8][tx] = W[(size_t)(k0 + ty + i * 8) * 1024 + n0 + tx];
  __syncthreads();
#pragma unroll
  for (int i = 0; i < 4; i++)
    Wt[(size_t)(n0 + ty + i * 8) * 1024 + k0 + tx] = f2bf(tile[tx][ty + i * 8]);
}

// ------- 64x128 MFMA GEMM tile (ogemm-v3 geometry + bias/scale/ldc) -------------
// R12: proj was latency-bound at 3 blocks/CU (47.3us, all pipes <35%). Retile
// 128x128 -> 64x128 doubles blocks/CU (768->1536 = 6/CU, 24 waves/CU) — the
// same occupancy lever that fixed attn (R5, +10%). Body is the ORIGINAL
// 2-barrier single-buffer idiom (every schedule/layout graft regressed:
// R7 null, R8 -15us, R10 -5us); geometry changes are proven safe (ogemm v3).
// Per-output math and accumulation order identical -> bit-identical C.
__device__ __forceinline__ void gemm_tile64(
    const u16* __restrict__ A, int lda, const u16* __restrict__ Bt, int ldb,
    const float* __restrict__ bias, bool brow, float scale,
    u16* __restrict__ Cb, float* __restrict__ Cf,
    int ldc, int bm, int bn, int K) {
  __shared__ alignas(16) u16 As[64 * 32];
  __shared__ alignas(16) u16 Bs[128 * 32];
  const int tid = threadIdx.x;
  const int wave = tid >> 6, lane = tid & 63;
  const int lm = lane & 15, kq = lane >> 4;
  const int g1 = tid, g2 = tid + 256;
  const u16* Ag  = A + (size_t)(bm + (g1 >> 2)) * lda + (g1 & 3) * 8;
  const u16* Bg1 = Bt + (size_t)(bn + (g1 >> 2)) * ldb + (g1 & 3) * 8;
  const u16* Bg2 = Bt + (size_t)(bn + (g2 >> 2)) * ldb + (g2 & 3) * 8;
  u16* lA  = &As[g1 * 8];
  u16* lB1 = &Bs[g1 * 8]; u16* lB2 = &Bs[g2 * 8];
  const int wm = (wave >> 1) * 32, wn = (wave & 1) * 64;

  f32x4 acc[2][4] = {};
  for (int k0 = 0; k0 < K; k0 += 32) {
    __syncthreads();
    load_lds16(Ag + k0, lA);
    load_lds16(Bg1 + k0, lB1);
    load_lds16(Bg2 + k0, lB2);
    __syncthreads();
    bf16x8 a[2], b[4];
#pragma unroll
    for (int t = 0; t < 2; t++)
      a[t] = *(const bf16x8*)&As[(wm + t * 16 + lm) * 32 + kq * 8];
#pragma unroll
    for (int t = 0; t < 4; t++)
      b[t] = *(const bf16x8*)&Bs[(wn + t * 16 + lm) * 32 + kq * 8];
#pragma unroll
    for (int mt = 0; mt < 2; mt++)
#pragma unroll
      for (int nt = 0; nt < 4; nt++)
        acc[mt][nt] = mfma16(a[mt], b[nt], acc[mt][nt]);
  }
  // epilogue: C/D layout col=lane&15, row=(lane>>4)*4+r
#pragma unroll
  for (int mt = 0; mt < 2; mt++) {
    float rb[4];
#pragma unroll
    for (int r = 0; r < 4; r++)
      rb[r] = (bias && brow) ? bias[bm + wm + mt * 16 + kq * 4 + r] : 0.f;
#pragma unroll
    for (int nt = 0; nt < 4; nt++) {
      const int col = bn + wn + nt * 16 + lm;
      const float cb = (bias && !brow) ? bias[col] : 0.f;
#pragma unroll
      for (int r = 0; r < 4; r++) {
        const int row = bm + wm + mt * 16 + kq * 4 + r;
        const size_t idx = (size_t)row * ldc + col;
        const float v = (acc[mt][nt][r] + rb[r] + cb) * scale;
        if (Cf) Cf[idx] = v;
        else    Cb[idx] = f2bf(v);
      }
    }
  }
}

// ---- fused projections, 64x128 tiles: 0..511 Q, 512..1023 K, 1024..1535 V^T ----
// XCD swizzle per segment: same-XCD blocks share A-rows / B-panels -> L2 reuse.
__global__ __launch_bounds__(256) void proj_gemm_kernel(
    const u16* __restrict__ Xq, const u16* __restrict__ Xkv,
    const u16* __restrict__ Wqt, const u16* __restrict__ Wkt, const u16* __restrict__ Wvt,
    const float* __restrict__ bq, const float* __restrict__ bk, const float* __restrict__ bv,
    u16* __restrict__ Qp, u16* __restrict__ Kp, u16* __restrict__ Vt, float qscale) {
  const int bid = blockIdx.x;
  const u16 *A, *Bt; const float* bias; u16* C;
  bool brow = false; float sc = 1.f; int ldc = 1024; int bm, bn;
  if (bid < 1024) {
    const int r = bid & 511;
    const int xcd = r & 7, s = r >> 3;            // s in [0,64)
    bm = (xcd * 8 + (s >> 3)) * 64;               // 64 m-tiles of 64 rows
    bn = (s & 7) * 128;                           // 8 n-tiles
    if (bid < 512) { A = Xq;  Bt = Wqt; bias = bq; C = Qp; sc = qscale; }
    else           { A = Xkv; Bt = Wkt; bias = bk; C = Kp; ldc = LDK;  }
  } else {
    int r = bid - 1024;                           // [0,512)
    const int z = r >> 8; r &= 255;
    const int xcd = r & 7, s = r >> 3;            // s in [0,32)
    bm = (xcd * 2 + (s >> 4)) * 64;               // 16 m-tiles (1024 hd rows)
    bn = (s & 15) * 128;                          // 16 n-tiles (2048 kv cols)
    A = Wvt; Bt = Xkv + (size_t)z * 2048 * 1024; bias = bv; brow = true;
    C = Vt + (size_t)z * 1024 * LDV; ldc = LDV;
  }
  gemm_tile64(A, 1024, Bt, 1024, bias, brow, sc, C, nullptr, ldc, bm, bn, 1024);
}

// ---- output projection v3: single-K, 64x128 tiles, 512 blocks, ONE fp32 X -----
__global__ __launch_bounds__(256) void ogemm_kernel(
    const u16* __restrict__ Ctx, const u16* __restrict__ Wot,
    float* __restrict__ X) {
  const int lin = blockIdx.x;                    // [0,512)
  const int xcd = lin & 7, s = lin >> 3;         // s in [0,64)
  const int bm = (xcd * 8 + (s >> 3)) * 64;      // 64 m-tiles of 64 rows
  const int bn = (s & 7) * 128;                  // 8 n-tiles of 128 cols
  gemm_tile64(Ctx, 1024, Wot, 1024, nullptr, false, 1.f,
              nullptr, X, 1024, bm, bn, 1024);
}

// ---------------- flash attention v12 (best measured: 44.5us) -------------------
// 512 blocks x 512 threads: waves 0-3 own kv[0,1024), waves 4-7 kv[1024,2048)
// of the SAME 128-q block; 32 q/wave. Carried: K/V 16B-slot involution
// (conflicts=0), in-register P via permlane32/16_swap, counted vmcnt(4)
// double-buffer, end-of-kernel kv-half combine via LDS (exact, no-max softmax).
__global__ __launch_bounds__(512, 4) void attn_kernel(
    const u16* __restrict__ Qp, const u16* __restrict__ Kp,
    const u16* __restrict__ Vt, u16* __restrict__ ctx) {
  __shared__ alignas(16) u16 smem[32768];
  const int tid = threadIdx.x;
  const int wave = tid >> 6, lane = tid & 63;
  const int kh = wave >> 2, w4 = wave & 3;   // kv-half, role within half
  const int lm = lane & 15, kq = lane >> 4;
  // XCD swizzle: L%8 = xcd; 16 consecutive slots per (b,h) combo
  const int L = blockIdx.x;
  const int xcd = L & 7, s = L >> 3;      // s in [0,64)
  const int combo = xcd + 8 * (s >> 4);   // [0,32)
  const int qb = s & 15;
  const int h = combo & 15, b = combo >> 4;
  const int qbase = qb * 128 + w4 * 32;

  u16* Ksh = smem + kh * 8192;            // + buf*4096
  u16* Vsh = smem + 16384 + kh * 8192;

  // Q B-frags (n=q=lm, k=hd), log2-domain pre-scaled
  bf16x8 qf[2][2];
#pragma unroll
  for (int qt = 0; qt < 2; qt++)
#pragma unroll
    for (int kc = 0; kc < 2; kc++)
      qf[qt][kc] = *(const bf16x8*)(Qp + (size_t)(b * 2048 + qbase + qt * 16 + lm) * 1024 +
                                    h * 64 + kc * 32 + kq * 8);

  // all-ones A-fragment for the l-sum MFMA
  union { u16 u[8]; bf16x8 v; } uo;
#pragma unroll
  for (int i = 0; i < 8; i++) uo.u[i] = 0x3F80;
  const bf16x8 ones = uo.v;

  const u16* Kb = Kp + ((size_t)b * 2048 + kh * 1024) * LDK + h * 64;
  const u16* Vb = Vt + (size_t)(b * 1024 + h * 64) * LDV + kh * 1024;
  // staging: physical 16B slot = lane; it fetches LOGICAL slot sp = lane^((lane>>3)&7)
  const int sp = lane ^ ((lane >> 3) & 7);
  const int c4 = sp >> 2, c3 = sp & 3;          // logical (row, k-quarter) in chunk
  // read side: logical slot (lm*4+kq) lives at physical slot (lm*4+kq)^(lm>>1)
  const int kvsw = ((lm * 4 + kq) ^ (lm >> 1)) * 8;

  f32x4 o[4][2] = {};
  f32x4 lsum[2] = {};

  // ---- prologue: stage tile 0 of this half into buf 0 ----
#pragma unroll
  for (int j = 0; j < 2; j++) {
    const int ii = w4 * 2 + j;
    const u16* gk = Kb + (size_t)(16 * (ii & 3) + c4) * LDK + (ii >> 2) * 32 + c3 * 8;
    load_lds16(gk, &Ksh[ii * 512 + lane * 8]);
    const u16* gv = Vb + (size_t)(16 * (ii & 3) + c4) * LDV + (ii >> 2) * 32 + c3 * 8;
    load_lds16(gv, &Vsh[ii * 512 + lane * 8]);
  }

  int cur = 0;
  for (int t = 0; t < 16; ++t) {
    if (t < 15) {
      // ---- issue tile t+1 loads into buf^1 (affine kvn -> strength-reduced) ----
      const int kvn = (t + 1) * 64;
      const int nb = (cur ^ 1) * 4096;
#pragma unroll
      for (int j = 0; j < 2; j++) {
        const int ii = w4 * 2 + j;
        const u16* gk = Kb + (size_t)(kvn + 16 * (ii & 3) + c4) * LDK + (ii >> 2) * 32 + c3 * 8;
        load_lds16(gk, &Ksh[nb + ii * 512 + lane * 8]);
        const u16* gv = Vb + (size_t)(16 * (ii & 3) + c4) * LDV + kvn + (ii >> 2) * 32 + c3 * 8;
        load_lds16(gv, &Vsh[nb + ii * 512 + lane * 8]);
      }
      __builtin_amdgcn_sched_barrier(0);
      // own tile-t loads landed; tile-(t+1)'s 4 stay in flight across the
      // barrier (T4: never vmcnt(0) mid-loop).
      asm volatile("s_waitcnt vmcnt(4)" ::: "memory");
    } else {
      __builtin_amdgcn_sched_barrier(0);
      asm volatile("s_waitcnt vmcnt(0)" ::: "memory");  // epilogue drain
    }
    __builtin_amdgcn_sched_barrier(0);
    __builtin_amdgcn_s_barrier();   // cross-wave: everyone's tile-t loads visible

    const int cb = cur * 4096;
    __builtin_amdgcn_s_setprio(1);

    // ---- hoisted K fragments: 8 unique b128, shared by both qt ----
    bf16x8 kf[2][4];
#pragma unroll
    for (int kc = 0; kc < 2; kc++)
#pragma unroll
      for (int kvt = 0; kvt < 4; kvt++)
        kf[kc][kvt] = *(const bf16x8*)&Ksh[cb + kc * 2048 + kvt * 512 + kvsw];

    bf16x8 pf[2][2];   // [qt][s2] PV B-frags, built fully in-register
#pragma unroll
    for (int qt = 0; qt < 2; qt++) {
      // ---- S^T[kv][q] = K . Q^T ----
      f32x4 st[4] = {};
#pragma unroll
      for (int kc = 0; kc < 2; kc++)
#pragma unroll
        for (int kvt = 0; kvt < 4; kvt++)
          st[kvt] = mfma16(kf[kc][kvt], qf[qt][kc], st[kvt]);
      // ---- P = exp2(S') via mantissa magic; pack to bf16-pair dwords ----
      unsigned Xd[4][2];
#pragma unroll
      for (int kvt = 0; kvt < 4; kvt++) {
        const unsigned e0 = __float_as_uint(fmaf(st[kvt][0], 128.f, EXPM16));
        const unsigned e1 = __float_as_uint(fmaf(st[kvt][1], 128.f, EXPM16));
        const unsigned e2 = __float_as_uint(fmaf(st[kvt][2], 128.f, EXPM16));
        const unsigned e3 = __float_as_uint(fmaf(st[kvt][3], 128.f, EXPM16));
        Xd[kvt][0] = __builtin_amdgcn_perm(e1, e0, 0x05040100u);  // kv {+0,+1}
        Xd[kvt][1] = __builtin_amdgcn_perm(e3, e2, 0x05040100u);  // kv {+2,+3}
      }
      // ---- lane redistribution C/D->B: per (kvt-pair K1, dword j):
      //      permlane32_swap then permlane16_swap ----
#pragma unroll
      for (int K1 = 0; K1 < 2; K1++) {
        unsigned a0 = Xd[2 * K1][0], b0 = Xd[2 * K1 + 1][0];
        unsigned a1 = Xd[2 * K1][1], b1 = Xd[2 * K1 + 1][1];
        asm("v_permlane32_swap_b32 %0, %1\n\t"
            "v_permlane16_swap_b32 %0, %1"
            : "+v"(a0), "+v"(b0));
        asm("v_permlane32_swap_b32 %0, %1\n\t"
            "v_permlane16_swap_b32 %0, %1"
            : "+v"(a1), "+v"(b1));
        union { uint4 u; bf16x8 v; } c;
        c.u.x = a0; c.u.y = a1; c.u.z = b0; c.u.w = b1;
        pf[qt][K1] = c.v;
      }
    }
    // ---- O^T[hd][q] += V^T . P^T ; l += ones . P^T (matrix pipe) ----
#pragma unroll
    for (int s2 = 0; s2 < 2; s2++) {
      bf16x8 vf[4];
#pragma unroll
      for (int hdt = 0; hdt < 4; hdt++)
        vf[hdt] = *(const bf16x8*)&Vsh[cb + s2 * 2048 + hdt * 512 + kvsw];
#pragma unroll
      for (int qt = 0; qt < 2; qt++) {
        lsum[qt] = mfma16(ones, pf[qt][s2], lsum[qt]);
#pragma unroll
        for (int hdt = 0; hdt < 4; hdt++)
          o[hdt][qt] = mfma16(vf[hdt], pf[qt][s2], o[hdt][qt]);
      }
    }
    __builtin_amdgcn_s_setprio(0);
    __builtin_amdgcn_sched_barrier(0);
    // reads of buf[cur] consumed -> next iter may overwrite after this barrier
    __builtin_amdgcn_s_barrier();
    cur ^= 1;
  }

  // ---- combine the two kv-halves via LDS (exact: O=O0+O1, l=l0+l1) ----
  __syncthreads();            // all K/V LDS reads done; smem reusable
  float* ex = (float*)smem;   // [w4][lane][36 f32] = 36.9KB, 16B-aligned rows
  const int exi = (w4 * 64 + lane) * 36;
  if (kh == 1) {
#pragma unroll
    for (int qt = 0; qt < 2; qt++)
#pragma unroll
      for (int hdt = 0; hdt < 4; hdt++)
        *(f32x4*)&ex[exi + (qt * 4 + hdt) * 4] = o[hdt][qt];
    ex[exi + 32] = lsum[0][0];
    ex[exi + 33] = lsum[1][0];
  }
  __syncthreads();
  if (kh == 0) {
#pragma unroll
    for (int qt = 0; qt < 2; qt++) {
      const float lo = ex[exi + 32 + qt];
      const float rl = 1.f / (lsum[qt][0] + lo);
      u16* cbp = ctx + (size_t)(b * 2048 + qbase + qt * 16 + lm) * 1024 + h * 64 + kq * 4;
#pragma unroll
      for (int hdt = 0; hdt < 4; hdt++) {
        const f32x4 op = *(const f32x4*)&ex[exi + (qt * 4 + hdt) * 4];
        u16x4 w;
#pragma unroll
        for (int r = 0; r < 4; r++) w[r] = f2bf((o[hdt][qt][r] + op[r]) * rl);
        *(u16x4*)(cbp + hdt * 16) = w;
      }
    }
  }
}

// ------- LayerNorm: x = X + query + bo, then LN; one block per row --------------
__global__ __launch_bounds__(256) void ln_kernel(
    const float* __restrict__ x0,
    const float* __restrict__ q, const float* __restrict__ bo,
    const float* __restrict__ gamma, const float* __restrict__ beta,
    float* __restrict__ out) {
  const int row = blockIdx.x;
  const int t = threadIdx.x;
  const size_t g = (size_t)row * 256 + t;
  const float4 a = ((const float4*)x0)[g];
  const float4 d = ((const float4*)q)[g];
  const float4 bv = ((const float4*)bo)[t];
  float4 v;
  v.x = a.x + d.x + bv.x;
  v.y = a.y + d.y + bv.y;
  v.z = a.z + d.z + bv.z;
  v.w = a.w + d.w + bv.w;
  float s = v.x + v.y + v.z + v.w;
  float s2 = v.x * v.x + v.y * v.y + v.z * v.z + v.w * v.w;
#pragma unroll
  for (int m = 1; m < 64; m <<= 1) {
    s += __shfl_xor(s, m);
    s2 += __shfl_xor(s2, m);
  }
  __shared__ float red[8];
  const int wave = t >> 6, lane = t & 63;
  if (lane == 0) { red[wave] = s; red[4 + wave] = s2; }
  __syncthreads();
  s = red[0] + red[1] + red[2] + red[3];
  s2 = red[4] + red[5] + red[6] + red[7];
  const float mu = s * (1.f / 1024.f);
  const float var = s2 * (1.f / 1024.f) - mu * mu;
  const float rstd = rsqrtf(var + 1e-5f);
  const float4 gm = ((const float4*)gamma)[t];
  const float4 bt = ((const float4*)beta)[t];
  float4 o;
  o.x = (v.x - mu) * rstd * gm.x + bt.x;
  o.y = (v.y - mu) * rstd * gm.y + bt.y;
  o.z = (v.z - mu) * rstd * gm.z + bt.z;
  o.w = (v.w - mu) * rstd * gm.w + bt.w;
  ((float4*)(out + (size_t)row * 1024))[t] = o;
}

extern "C" void kernel_launch(void* const* d_in, const int* in_sizes, int n_in,
                              void* d_out, int out_size, void* d_ws, size_t ws_size,
                              hipStream_t stream) {
  const float* query     = (const float*)d_in[0];
  const float* key_value = (const float*)d_in[1];
  const float* Wq = (const float*)d_in[2];
  const float* bq = (const float*)d_in[3];
  const float* Wk = (const float*)d_in[4];
  const float* bk = (const float*)d_in[5];
  const float* Wv = (const float*)d_in[6];
  const float* bv = (const float*)d_in[7];
  const float* Wo = (const float*)d_in[8];
  const float* bo = (const float*)d_in[9];
  const float* gamma = (const float*)d_in[10];
  const float* beta  = (const float*)d_in[11];
  float* out = (float*)d_out;

  const size_t MT = (size_t)4096 * 1024;  // tokens x hid
  const size_t WT = (size_t)1024 * 1024;
  char* ws = (char*)d_ws;
  u16* Xq  = (u16*)ws; ws += MT * 2;
  u16* Xkv = (u16*)ws; ws += MT * 2;
  u16* Wqt = (u16*)ws; ws += WT * 2;
  u16* Wkt = (u16*)ws; ws += WT * 2;
  u16* Wvt = (u16*)ws; ws += WT * 2;
  u16* Wot = (u16*)ws; ws += WT * 2;
  u16* Qp  = (u16*)ws; ws += MT * 2;
  u16* Kp  = (u16*)ws; ws += (size_t)4096 * LDK * 2;
  u16* Vt  = (u16*)ws; ws += (size_t)2048 * LDV * 2;   // [b][hd 1024][kv 2048 pad 2080]
  float* X0 = (float*)ws; ws += MT * 4;
  u16* Ctx = Xq;   // alias: Xq dead after proj_gemm; Ctx written by attn

  const float qscale = 0.125f * LOG2E;

  pre_kernel<<<12288, 256, 0, stream>>>(query, key_value, Xq, Xkv,
                                        Wq, Wk, Wv, Wo, Wqt, Wkt, Wvt, Wot);
  proj_gemm_kernel<<<1536, 256, 0, stream>>>(Xq, Xkv, Wqt, Wkt, Wvt, bq, bk, bv,
                                             Qp, Kp, Vt, qscale);
  attn_kernel<<<512, 512, 0, stream>>>(Qp, Kp, Vt, Ctx);
  ogemm_kernel<<<512, 256, 0, stream>>>(Ctx, Wot, X0);
  ln_kernel<<<4096, 256, 0, stream>>>(X0, query, bo, gamma, beta, out);
}

// Round 13
// 208.661 us; speedup vs baseline: 1.0656x; 1.0656x over previous
//
#include <hip/hip_runtime.h>

typedef unsigned short u16;
typedef __bf16 bf16x8 __attribute__((ext_vector_type(8)));
typedef float f32x4 __attribute__((ext_vector_type(4)));
typedef unsigned short u16x4 __attribute__((ext_vector_type(4)));

#define LOG2E 1.44269504088896340736f
#define LDK 1040   // padded Kp row (u16): breaks 2KB channel aliasing
#define LDV 2080   // padded Vt row (u16): breaks 4KB channel aliasing
// mantissa-magic exp2->bf16: fmaf(s,128,12582912+16248) quantizes s*128+16248
// into the fp32 mantissa; low 16 bits are bf16 of ~2^s (Mineiro, bf16-direct).
#define EXPM16 12599160.0f

__device__ __forceinline__ u16 f2bf(float f) {
  unsigned u = __float_as_uint(f);
  u += 0x7FFFu + ((u >> 16) & 1u);
  return (u16)(u >> 16);
}

__device__ __forceinline__ void load_lds16(const void* g, void* l) {
  __builtin_amdgcn_global_load_lds(
      (__attribute__((address_space(1))) void*)g,
      (__attribute__((address_space(3))) void*)l, 16, 0, 0);
}

__device__ __forceinline__ f32x4 mfma16(bf16x8 a, bf16x8 b, f32x4 c) {
  return __builtin_amdgcn_mfma_f32_16x16x32_bf16(a, b, c, 0, 0, 0);
}

// ------- merged pre-pass: blocks [0,8192) cast q/kv -> bf16; [8192,12288) W^T ----
__global__ __launch_bounds__(256) void pre_kernel(
    const float* __restrict__ q, const float* __restrict__ kv,
    u16* __restrict__ Xq, u16* __restrict__ Xkv,
    const float* __restrict__ Wq, const float* __restrict__ Wk,
    const float* __restrict__ Wv, const float* __restrict__ Wo,
    u16* __restrict__ Wqt, u16* __restrict__ Wkt,
    u16* __restrict__ Wvt, u16* __restrict__ Wot) {
  __shared__ float tile[32][33];
  const int bid = blockIdx.x;
  if (bid < 8192) {
    const int n4each = 4096 * 256;
    int i = bid * 256 + threadIdx.x;
    const float* src; u16* dst; int j;
    if (i < n4each) { src = q; dst = Xq; j = i; }
    else            { src = kv; dst = Xkv; j = i - n4each; }
    const float4 v = ((const float4*)src)[j];
    u16x4 o;
    o.x = f2bf(v.x); o.y = f2bf(v.y); o.z = f2bf(v.z); o.w = f2bf(v.w);
    ((u16x4*)dst)[j] = o;
    return;
  }
  const int t = bid - 8192;
  const int z = t >> 10, rem = t & 1023;
  const float* W; u16* Wt;
  switch (z) {
    case 0: W = Wq; Wt = Wqt; break;
    case 1: W = Wk; Wt = Wkt; break;
    case 2: W = Wv; Wt = Wvt; break;
    default: W = Wo; Wt = Wot; break;
  }
  const int tx = threadIdx.x & 31, ty = threadIdx.x >> 5;  // 32x8
  const int n0 = (rem & 31) * 32, k0 = (rem >> 5) * 32;
#pragma unroll
  for (int i = 0; i < 4; i++)
    tile[ty + i * 8][tx] = W[(size_t)(k0 + ty + i * 8) * 1024 + n0 + tx];
  __syncthreads();
#pragma unroll
  for (int i = 0; i < 4; i++)
    Wt[(size_t)(n0 + ty + i * 8) * 1024 + k0 + tx] = f2bf(tile[tx][ty + i * 8]);
}

// ------- 128x128 GEMM tile, 8 waves (512 thr): occupancy without traffic --------
// R13: R12's 64x128 retile regressed because FETCH_SIZE rose 36->57GB (halved
// A-reuse). The correct occupancy lever keeps the TILE (same reuse, same
// fetch) and adds waves per block: 8 waves, each computing a 32x64 slice
// (acc 2x4, ~48 VGPR) -> 3 blocks/CU x 8 = 24 waves/CU (6/SIMD), 2x latency
// hiding vs the 4-wave version. Staging: each of 512 threads loads one A
// 16B-slot + one B slot per K-step. Same ORIGINAL 2-barrier schedule (every
// schedule/layout graft regressed: R7 null, R8 -15us, R10 -5us). Per-output
// K-order identical -> bit-identical C.
__device__ __forceinline__ void gemm_tile512(
    const u16* __restrict__ A, int lda, const u16* __restrict__ Bt, int ldb,
    const float* __restrict__ bias, bool brow, float scale,
    u16* __restrict__ Cb, float* __restrict__ Cf,
    int ldc, int bm, int bn, int K) {
  __shared__ alignas(16) u16 As[128 * 32];
  __shared__ alignas(16) u16 Bs[128 * 32];
  const int tid = threadIdx.x;               // [0,512)
  const int wave = tid >> 6, lane = tid & 63;
  const int lm = lane & 15, kq = lane >> 4;
  const u16* Ag = A + (size_t)(bm + (tid >> 2)) * lda + (tid & 3) * 8;
  const u16* Bg = Bt + (size_t)(bn + (tid >> 2)) * ldb + (tid & 3) * 8;
  u16* lA = &As[tid * 8];
  u16* lB = &Bs[tid * 8];
  const int wm = (wave >> 1) * 32, wn = (wave & 1) * 64;  // 4m x 2n wave grid

  f32x4 acc[2][4] = {};
  for (int k0 = 0; k0 < K; k0 += 32) {
    __syncthreads();
    load_lds16(Ag + k0, lA);
    load_lds16(Bg + k0, lB);
    __syncthreads();
    bf16x8 a[2], b[4];
#pragma unroll
    for (int t = 0; t < 2; t++)
      a[t] = *(const bf16x8*)&As[(wm + t * 16 + lm) * 32 + kq * 8];
#pragma unroll
    for (int t = 0; t < 4; t++)
      b[t] = *(const bf16x8*)&Bs[(wn + t * 16 + lm) * 32 + kq * 8];
#pragma unroll
    for (int mt = 0; mt < 2; mt++)
#pragma unroll
      for (int nt = 0; nt < 4; nt++)
        acc[mt][nt] = mfma16(a[mt], b[nt], acc[mt][nt]);
  }
  // epilogue: C/D layout col=lane&15, row=(lane>>4)*4+r
#pragma unroll
  for (int mt = 0; mt < 2; mt++) {
    float rb[4];
#pragma unroll
    for (int r = 0; r < 4; r++)
      rb[r] = (bias && brow) ? bias[bm + wm + mt * 16 + kq * 4 + r] : 0.f;
#pragma unroll
    for (int nt = 0; nt < 4; nt++) {
      const int col = bn + wn + nt * 16 + lm;
      const float cb = (bias && !brow) ? bias[col] : 0.f;
#pragma unroll
      for (int r = 0; r < 4; r++) {
        const int row = bm + wm + mt * 16 + kq * 4 + r;
        const size_t idx = (size_t)row * ldc + col;
        const float v = (acc[mt][nt][r] + rb[r] + cb) * scale;
        if (Cf) Cf[idx] = v;
        else    Cb[idx] = f2bf(v);
      }
    }
  }
}

// ------- 64x128 GEMM tile (ogemm v3 geometry; R11-proven) -----------------------
__device__ __forceinline__ void gemm_tile64(
    const u16* __restrict__ A, int lda, const u16* __restrict__ Bt, int ldb,
    float* __restrict__ Cf, int ldc, int bm, int bn, int K) {
  __shared__ alignas(16) u16 As[64 * 32];
  __shared__ alignas(16) u16 Bs[128 * 32];
  const int tid = threadIdx.x;
  const int wave = tid >> 6, lane = tid & 63;
  const int lm = lane & 15, kq = lane >> 4;
  const int g1 = tid, g2 = tid + 256;
  const u16* Ag  = A + (size_t)(bm + (g1 >> 2)) * lda + (g1 & 3) * 8;
  const u16* Bg1 = Bt + (size_t)(bn + (g1 >> 2)) * ldb + (g1 & 3) * 8;
  const u16* Bg2 = Bt + (size_t)(bn + (g2 >> 2)) * ldb + (g2 & 3) * 8;
  u16* lA  = &As[g1 * 8];
  u16* lB1 = &Bs[g1 * 8]; u16* lB2 = &Bs[g2 * 8];
  const int wm = (wave >> 1) * 32, wn = (wave & 1) * 64;

  f32x4 acc[2][4] = {};
  for (int k0 = 0; k0 < K; k0 += 32) {
    __syncthreads();
    load_lds16(Ag + k0, lA);
    load_lds16(Bg1 + k0, lB1);
    load_lds16(Bg2 + k0, lB2);
    __syncthreads();
    bf16x8 a[2], b[4];
#pragma unroll
    for (int t = 0; t < 2; t++)
      a[t] = *(const bf16x8*)&As[(wm + t * 16 + lm) * 32 + kq * 8];
#pragma unroll
    for (int t = 0; t < 4; t++)
      b[t] = *(const bf16x8*)&Bs[(wn + t * 16 + lm) * 32 + kq * 8];
#pragma unroll
    for (int mt = 0; mt < 2; mt++)
#pragma unroll
      for (int nt = 0; nt < 4; nt++)
        acc[mt][nt] = mfma16(a[mt], b[nt], acc[mt][nt]);
  }
#pragma unroll
  for (int mt = 0; mt < 2; mt++)
#pragma unroll
    for (int nt = 0; nt < 4; nt++) {
      const int col = bn + wn + nt * 16 + lm;
#pragma unroll
      for (int r = 0; r < 4; r++) {
        const int row = bm + wm + mt * 16 + kq * 4 + r;
        Cf[(size_t)row * ldc + col] = acc[mt][nt][r];
      }
    }
}

// ---- fused projections: blocks 0..255 Q-proj, 256..511 K-proj, 512..767 V^T ----
// R11 block->tile mapping (128x128, FETCH ~36GB); 512-thread 8-wave body.
__global__ __launch_bounds__(512, 6) void proj_gemm_kernel(
    const u16* __restrict__ Xq, const u16* __restrict__ Xkv,
    const u16* __restrict__ Wqt, const u16* __restrict__ Wkt, const u16* __restrict__ Wvt,
    const float* __restrict__ bq, const float* __restrict__ bk, const float* __restrict__ bv,
    u16* __restrict__ Qp, u16* __restrict__ Kp, u16* __restrict__ Vt, float qscale) {
  const int bid = blockIdx.x;
  const u16 *A, *Bt; const float* bias; u16* C;
  bool brow = false; float sc = 1.f; int ldc = 1024; int bm, bn;
  if (bid < 512) {
    const int r = bid & 255;
    const int xcd = r & 7, s = r >> 3;            // xcd owns 4 m-panels x 8 n-panels
    bm = (xcd * 4 + (s >> 3)) * 128;
    bn = (s & 7) * 128;
    if (bid < 256) { A = Xq;  Bt = Wqt; bias = bq; C = Qp; sc = qscale; }
    else           { A = Xkv; Bt = Wkt; bias = bk; C = Kp; ldc = LDK;  }
  } else {
    int r = bid - 512;
    const int z = r >> 7; r &= 127;               // 8 bm x 16 bn per batch half
    const int xcd = r & 7, s = r >> 3;            // s in [0,16)
    bm = (s >> 1) * 128;                          // [0,8) m-panels
    bn = (xcd * 2 + (s & 1)) * 128;               // 2 bn-panels per xcd
    A = Wvt; Bt = Xkv + (size_t)z * 2048 * 1024; bias = bv; brow = true;
    C = Vt + (size_t)z * 1024 * LDV; ldc = LDV;
  }
  gemm_tile512(A, 1024, Bt, 1024, bias, brow, sc, C, nullptr, ldc, bm, bn, 1024);
}

// ---- output projection v3: single-K, 64x128 tiles, 512 blocks, ONE fp32 X -----
__global__ __launch_bounds__(256) void ogemm_kernel(
    const u16* __restrict__ Ctx, const u16* __restrict__ Wot,
    float* __restrict__ X) {
  const int lin = blockIdx.x;                    // [0,512)
  const int xcd = lin & 7, s = lin >> 3;         // s in [0,64)
  const int bm = (xcd * 8 + (s >> 3)) * 64;      // 64 m-tiles of 64 rows
  const int bn = (s & 7) * 128;                  // 8 n-tiles of 128 cols
  gemm_tile64(Ctx, 1024, Wot, 1024, X, 1024, bm, bn, 1024);
}

// ---------------- flash attention v12 (best measured: 44.5us) -------------------
// 512 blocks x 512 threads: waves 0-3 own kv[0,1024), waves 4-7 kv[1024,2048)
// of the SAME 128-q block; 32 q/wave. Carried: K/V 16B-slot involution
// (conflicts=0), in-register P via permlane32/16_swap, counted vmcnt(4)
// double-buffer, end-of-kernel kv-half combine via LDS (exact, no-max softmax).
__global__ __launch_bounds__(512, 4) void attn_kernel(
    const u16* __restrict__ Qp, const u16* __restrict__ Kp,
    const u16* __restrict__ Vt, u16* __restrict__ ctx) {
  __shared__ alignas(16) u16 smem[32768];
  const int tid = threadIdx.x;
  const int wave = tid >> 6, lane = tid & 63;
  const int kh = wave >> 2, w4 = wave & 3;   // kv-half, role within half
  const int lm = lane & 15, kq = lane >> 4;
  // XCD swizzle: L%8 = xcd; 16 consecutive slots per (b,h) combo
  const int L = blockIdx.x;
  const int xcd = L & 7, s = L >> 3;      // s in [0,64)
  const int combo = xcd + 8 * (s >> 4);   // [0,32)
  const int qb = s & 15;
  const int h = combo & 15, b = combo >> 4;
  const int qbase = qb * 128 + w4 * 32;

  u16* Ksh = smem + kh * 8192;            // + buf*4096
  u16* Vsh = smem + 16384 + kh * 8192;

  // Q B-frags (n=q=lm, k=hd), log2-domain pre-scaled
  bf16x8 qf[2][2];
#pragma unroll
  for (int qt = 0; qt < 2; qt++)
#pragma unroll
    for (int kc = 0; kc < 2; kc++)
      qf[qt][kc] = *(const bf16x8*)(Qp + (size_t)(b * 2048 + qbase + qt * 16 + lm) * 1024 +
                                    h * 64 + kc * 32 + kq * 8);

  // all-ones A-fragment for the l-sum MFMA
  union { u16 u[8]; bf16x8 v; } uo;
#pragma unroll
  for (int i = 0; i < 8; i++) uo.u[i] = 0x3F80;
  const bf16x8 ones = uo.v;

  const u16* Kb = Kp + ((size_t)b * 2048 + kh * 1024) * LDK + h * 64;
  const u16* Vb = Vt + (size_t)(b * 1024 + h * 64) * LDV + kh * 1024;
  // staging: physical 16B slot = lane; it fetches LOGICAL slot sp = lane^((lane>>3)&7)
  const int sp = lane ^ ((lane >> 3) & 7);
  const int c4 = sp >> 2, c3 = sp & 3;          // logical (row, k-quarter) in chunk
  // read side: logical slot (lm*4+kq) lives at physical slot (lm*4+kq)^(lm>>1)
  const int kvsw = ((lm * 4 + kq) ^ (lm >> 1)) * 8;

  f32x4 o[4][2] = {};
  f32x4 lsum[2] = {};

  // ---- prologue: stage tile 0 of this half into buf 0 ----
#pragma unroll
  for (int j = 0; j < 2; j++) {
    const int ii = w4 * 2 + j;
    const u16* gk = Kb + (size_t)(16 * (ii & 3) + c4) * LDK + (ii >> 2) * 32 + c3 * 8;
    load_lds16(gk, &Ksh[ii * 512 + lane * 8]);
    const u16* gv = Vb + (size_t)(16 * (ii & 3) + c4) * LDV + (ii >> 2) * 32 + c3 * 8;
    load_lds16(gv, &Vsh[ii * 512 + lane * 8]);
  }

  int cur = 0;
  for (int t = 0; t < 16; ++t) {
    if (t < 15) {
      // ---- issue tile t+1 loads into buf^1 (affine kvn -> strength-reduced) ----
      const int kvn = (t + 1) * 64;
      const int nb = (cur ^ 1) * 4096;
#pragma unroll
      for (int j = 0; j < 2; j++) {
        const int ii = w4 * 2 + j;
        const u16* gk = Kb + (size_t)(kvn + 16 * (ii & 3) + c4) * LDK + (ii >> 2) * 32 + c3 * 8;
        load_lds16(gk, &Ksh[nb + ii * 512 + lane * 8]);
        const u16* gv = Vb + (size_t)(16 * (ii & 3) + c4) * LDV + kvn + (ii >> 2) * 32 + c3 * 8;
        load_lds16(gv, &Vsh[nb + ii * 512 + lane * 8]);
      }
      __builtin_amdgcn_sched_barrier(0);
      // own tile-t loads landed; tile-(t+1)'s 4 stay in flight across the
      // barrier (T4: never vmcnt(0) mid-loop).
      asm volatile("s_waitcnt vmcnt(4)" ::: "memory");
    } else {
      __builtin_amdgcn_sched_barrier(0);
      asm volatile("s_waitcnt vmcnt(0)" ::: "memory");  // epilogue drain
    }
    __builtin_amdgcn_sched_barrier(0);
    __builtin_amdgcn_s_barrier();   // cross-wave: everyone's tile-t loads visible

    const int cb = cur * 4096;
    __builtin_amdgcn_s_setprio(1);

    // ---- hoisted K fragments: 8 unique b128, shared by both qt ----
    bf16x8 kf[2][4];
#pragma unroll
    for (int kc = 0; kc < 2; kc++)
#pragma unroll
      for (int kvt = 0; kvt < 4; kvt++)
        kf[kc][kvt] = *(const bf16x8*)&Ksh[cb + kc * 2048 + kvt * 512 + kvsw];

    bf16x8 pf[2][2];   // [qt][s2] PV B-frags, built fully in-register
#pragma unroll
    for (int qt = 0; qt < 2; qt++) {
      // ---- S^T[kv][q] = K . Q^T ----
      f32x4 st[4] = {};
#pragma unroll
      for (int kc = 0; kc < 2; kc++)
#pragma unroll
        for (int kvt = 0; kvt < 4; kvt++)
          st[kvt] = mfma16(kf[kc][kvt], qf[qt][kc], st[kvt]);
      // ---- P = exp2(S') via mantissa magic; pack to bf16-pair dwords ----
      unsigned Xd[4][2];
#pragma unroll
      for (int kvt = 0; kvt < 4; kvt++) {
        const unsigned e0 = __float_as_uint(fmaf(st[kvt][0], 128.f, EXPM16));
        const unsigned e1 = __float_as_uint(fmaf(st[kvt][1], 128.f, EXPM16));
        const unsigned e2 = __float_as_uint(fmaf(st[kvt][2], 128.f, EXPM16));
        const unsigned e3 = __float_as_uint(fmaf(st[kvt][3], 128.f, EXPM16));
        Xd[kvt][0] = __builtin_amdgcn_perm(e1, e0, 0x05040100u);  // kv {+0,+1}
        Xd[kvt][1] = __builtin_amdgcn_perm(e3, e2, 0x05040100u);  // kv {+2,+3}
      }
      // ---- lane redistribution C/D->B: per (kvt-pair K1, dword j):
      //      permlane32_swap then permlane16_swap ----
#pragma unroll
      for (int K1 = 0; K1 < 2; K1++) {
        unsigned a0 = Xd[2 * K1][0], b0 = Xd[2 * K1 + 1][0];
        unsigned a1 = Xd[2 * K1][1], b1 = Xd[2 * K1 + 1][1];
        asm("v_permlane32_swap_b32 %0, %1\n\t"
            "v_permlane16_swap_b32 %0, %1"
            : "+v"(a0), "+v"(b0));
        asm("v_permlane32_swap_b32 %0, %1\n\t"
            "v_permlane16_swap_b32 %0, %1"
            : "+v"(a1), "+v"(b1));
        union { uint4 u; bf16x8 v; } c;
        c.u.x = a0; c.u.y = a1; c.u.z = b0; c.u.w = b1;
        pf[qt][K1] = c.v;
      }
    }
    // ---- O^T[hd][q] += V^T . P^T ; l += ones . P^T (matrix pipe) ----
#pragma unroll
    for (int s2 = 0; s2 < 2; s2++) {
      bf16x8 vf[4];
#pragma unroll
      for (int hdt = 0; hdt < 4; hdt++)
        vf[hdt] = *(const bf16x8*)&Vsh[cb + s2 * 2048 + hdt * 512 + kvsw];
#pragma unroll
      for (int qt = 0; qt < 2; qt++) {
        lsum[qt] = mfma16(ones, pf[qt][s2], lsum[qt]);
#pragma unroll
        for (int hdt = 0; hdt < 4; hdt++)
          o[hdt][qt] = mfma16(vf[hdt], pf[qt][s2], o[hdt][qt]);
      }
    }
    __builtin_amdgcn_s_setprio(0);
    __builtin_amdgcn_sched_barrier(0);
    // reads of buf[cur] consumed -> next iter may overwrite after this barrier
    __builtin_amdgcn_s_barrier();
    cur ^= 1;
  }

  // ---- combine the two kv-halves via LDS (exact: O=O0+O1, l=l0+l1) ----
  __syncthreads();            // all K/V LDS reads done; smem reusable
  float* ex = (float*)smem;   // [w4][lane][36 f32] = 36.9KB, 16B-aligned rows
  const int exi = (w4 * 64 + lane) * 36;
  if (kh == 1) {
#pragma unroll
    for (int qt = 0; qt < 2; qt++)
#pragma unroll
      for (int hdt = 0; hdt < 4; hdt++)
        *(f32x4*)&ex[exi + (qt * 4 + hdt) * 4] = o[hdt][qt];
    ex[exi + 32] = lsum[0][0];
    ex[exi + 33] = lsum[1][0];
  }
  __syncthreads();
  if (kh == 0) {
#pragma unroll
    for (int qt = 0; qt < 2; qt++) {
      const float lo = ex[exi + 32 + qt];
      const float rl = 1.f / (lsum[qt][0] + lo);
      u16* cbp = ctx + (size_t)(b * 2048 + qbase + qt * 16 + lm) * 1024 + h * 64 + kq * 4;
#pragma unroll
      for (int hdt = 0; hdt < 4; hdt++) {
        const f32x4 op = *(const f32x4*)&ex[exi + (qt * 4 + hdt) * 4];
        u16x4 w;
#pragma unroll
        for (int r = 0; r < 4; r++) w[r] = f2bf((o[hdt][qt][r] + op[r]) * rl);
        *(u16x4*)(cbp + hdt * 16) = w;
      }
    }
  }
}

// ------- LayerNorm: x = X + query + bo, then LN; one block per row --------------
__global__ __launch_bounds__(256) void ln_kernel(
    const float* __restrict__ x0,
    const float* __restrict__ q, const float* __restrict__ bo,
    const float* __restrict__ gamma, const float* __restrict__ beta,
    float* __restrict__ out) {
  const int row = blockIdx.x;
  const int t = threadIdx.x;
  const size_t g = (size_t)row * 256 + t;
  const float4 a = ((const float4*)x0)[g];
  const float4 d = ((const float4*)q)[g];
  const float4 bv = ((const float4*)bo)[t];
  float4 v;
  v.x = a.x + d.x + bv.x;
  v.y = a.y + d.y + bv.y;
  v.z = a.z + d.z + bv.z;
  v.w = a.w + d.w + bv.w;
  float s = v.x + v.y + v.z + v.w;
  float s2 = v.x * v.x + v.y * v.y + v.z * v.z + v.w * v.w;
#pragma unroll
  for (int m = 1; m < 64; m <<= 1) {
    s += __shfl_xor(s, m);
    s2 += __shfl_xor(s2, m);
  }
  __shared__ float red[8];
  const int wave = t >> 6, lane = t & 63;
  if (lane == 0) { red[wave] = s; red[4 + wave] = s2; }
  __syncthreads();
  s = red[0] + red[1] + red[2] + red[3];
  s2 = red[4] + red[5] + red[6] + red[7];
  const float mu = s * (1.f / 1024.f);
  const float var = s2 * (1.f / 1024.f) - mu * mu;
  const float rstd = rsqrtf(var + 1e-5f);
  const float4 gm = ((const float4*)gamma)[t];
  const float4 bt = ((const float4*)beta)[t];
  float4 o;
  o.x = (v.x - mu) * rstd * gm.x + bt.x;
  o.y = (v.y - mu) * rstd * gm.y + bt.y;
  o.z = (v.z - mu) * rstd * gm.z + bt.z;
  o.w = (v.w - mu) * rstd * gm.w + bt.w;
  ((float4*)(out + (size_t)row * 1024))[t] = o;
}

extern "C" void kernel_launch(void* const* d_in, const int* in_sizes, int n_in,
                              void* d_out, int out_size, void* d_ws, size_t ws_size,
                              hipStream_t stream) {
  const float* query     = (const float*)d_in[0];
  const float* key_value = (const float*)d_in[1];
  const float* Wq = (const float*)d_in[2];
  const float* bq = (const float*)d_in[3];
  const float* Wk = (const float*)d_in[4];
  const float* bk = (const float*)d_in[5];
  const float* Wv = (const float*)d_in[6];
  const float* bv = (const float*)d_in[7];
  const float* Wo = (const float*)d_in[8];
  const float* bo = (const float*)d_in[9];
  const float* gamma = (const float*)d_in[10];
  const float* beta  = (const float*)d_in[11];
  float* out = (float*)d_out;

  const size_t MT = (size_t)4096 * 1024;  // tokens x hid
  const size_t WT = (size_t)1024 * 1024;
  char* ws = (char*)d_ws;
  u16* Xq  = (u16*)ws; ws += MT * 2;
  u16* Xkv = (u16*)ws; ws += MT * 2;
  u16* Wqt = (u16*)ws; ws += WT * 2;
  u16* Wkt = (u16*)ws; ws += WT * 2;
  u16* Wvt = (u16*)ws; ws += WT * 2;
  u16* Wot = (u16*)ws; ws += WT * 2;
  u16* Qp  = (u16*)ws; ws += MT * 2;
  u16* Kp  = (u16*)ws; ws += (size_t)4096 * LDK * 2;
  u16* Vt  = (u16*)ws; ws += (size_t)2048 * LDV * 2;   // [b][hd 1024][kv 2048 pad 2080]
  float* X0 = (float*)ws; ws += MT * 4;
  u16* Ctx = Xq;   // alias: Xq dead after proj_gemm; Ctx written by attn

  const float qscale = 0.125f * LOG2E;

  pre_kernel<<<12288, 256, 0, stream>>>(query, key_value, Xq, Xkv,
                                        Wq, Wk, Wv, Wo, Wqt, Wkt, Wvt, Wot);
  proj_gemm_kernel<<<768, 512, 0, stream>>>(Xq, Xkv, Wqt, Wkt, Wvt, bq, bk, bv,
                                            Qp, Kp, Vt, qscale);
  attn_kernel<<<512, 512, 0, stream>>>(Qp, Kp, Vt, Ctx);
  ogemm_kernel<<<512, 256, 0, stream>>>(Ctx, Wot, X0);
  ln_kernel<<<4096, 256, 0, stream>>>(X0, query, bo, gamma, beta, out);
}